// Round 8
// baseline (186.035 us; speedup 1.0000x reference)
//
#include <hip/hip_runtime.h>

// Problem constants (fixed by setup_inputs in the reference)
#define B_  8
#define N_  3072
#define C_  256
#define H_  128
#define W_  96
#define HW_ (H_ * W_)
#define NC_ (B_ * HW_)          // 98304 cells (~78% EMPTY: 0.25 tokens/cell)
#define NT_ (B_ * N_)           // 24576 tokens
#define EPSF 1e-6f

// Gaussian 3x3, sigma=2 (normalized): center, edge, corner
#define KW0 0.13080118f
#define KW1 0.11543166f
#define KW2 0.10186807f

// fused-kernel tiling
#define CG_ 64                  // channels per block
#define XH_ 48                  // x half-width per block
#define XS_ 50                  // staged columns (48 + 2 halo)
#define CP_ 65                  // channel pad (bank-conflict-free)

// ws layout (u32 units) — identical to the round-4-proven 900,104 B layout.
#define OFF_ASTART 0
#define OFF_ACUR   (NC_ + 1)
#define OFF_BSUM   (2 * NC_ + 1)
#define OFF_BOFF   (2 * NC_ + 1 + 384)
#define OFF_TOKS   (2 * NC_ + 1 + 768)
// total = 2*NC_+1+768+NT_ = 221953 u32 = 887,812 B

__device__ __forceinline__ void token_cell(const float* __restrict__ loc, int token,
                                           int& b, int& ix, int& iy) {
    b = token / N_;
    const float lx = fminf(fmaxf(loc[2 * token + 0], -1.0f), 1.0f);
    const float ly = fminf(fmaxf(loc[2 * token + 1], -1.0f), 1.0f);
    const float px = 0.5f * (lx + 1.0f) * (float)W_ - 0.5f;
    const float py = 0.5f * (ly + 1.0f) * (float)H_ - 0.5f;
    ix = (int)rintf(px); ix = min(max(ix, 0), W_ - 1);   // rintf = round-half-even = jnp.round
    iy = (int)rintf(py); iy = min(max(iy, 0), H_ - 1);
}

// Pass 1: histogram tokens into cells
__global__ void count_k(const float* __restrict__ loc, unsigned* __restrict__ cnts) {
    const int token = blockIdx.x * 256 + threadIdx.x;   // NT_ threads
    int b, ix, iy;
    token_cell(loc, token, b, ix, iy);
    atomicAdd(&cnts[b * HW_ + iy * W_ + ix], 1u);
}

// Pass 2a: per-block (256-cell) sums
__global__ void scanA(const unsigned* __restrict__ cnts, unsigned* __restrict__ Bsum) {
    const int i = blockIdx.x * 256 + threadIdx.x;
    int c = (int)cnts[i];
    #pragma unroll
    for (int off = 32; off > 0; off >>= 1) c += __shfl_down(c, off, 64);
    __shared__ int s[4];
    if ((threadIdx.x & 63) == 0) s[threadIdx.x >> 6] = c;
    __syncthreads();
    if (threadIdx.x == 0) Bsum[blockIdx.x] = (unsigned)(s[0] + s[1] + s[2] + s[3]);
}

// Pass 2b: exclusive scan of the 384 block sums (single block)
__global__ void scanB(const unsigned* __restrict__ Bsum, unsigned* __restrict__ Boff) {
    __shared__ unsigned s[512];
    const int t = threadIdx.x;
    const unsigned v = (t < 384) ? Bsum[t] : 0u;
    s[t] = v;
    __syncthreads();
    #pragma unroll
    for (int off = 1; off < 512; off <<= 1) {
        const unsigned a = (t >= off) ? s[t - off] : 0u;
        __syncthreads();
        s[t] += a;
        __syncthreads();
    }
    if (t < 384) Boff[t] = s[t] - v;   // exclusive
}

// Pass 2c: per-block exclusive scan + block offset -> Astart (and cursor copy)
__global__ void scanC(const unsigned* __restrict__ Boff,
                      unsigned* __restrict__ Astart, unsigned* __restrict__ Acur) {
    __shared__ unsigned s[256];
    const int t = threadIdx.x;
    const int i = blockIdx.x * 256 + t;
    const unsigned v = Acur[i];        // counts currently live in Acur
    s[t] = v;
    __syncthreads();
    #pragma unroll
    for (int off = 1; off < 256; off <<= 1) {
        const unsigned a = (t >= off) ? s[t - off] : 0u;
        __syncthreads();
        s[t] += a;
        __syncthreads();
    }
    const unsigned excl = s[t] - v + Boff[blockIdx.x];
    Astart[i] = excl;
    Acur[i]   = excl;                  // cursor starts at bin start
    if (i == 0) Astart[NC_] = NT_;     // total
}

// Pass 3: scatter token ids into bins
__global__ void fill_bins(const float* __restrict__ loc,
                          unsigned* __restrict__ Acur, unsigned* __restrict__ toks) {
    const int token = blockIdx.x * 256 + threadIdx.x;
    int b, ix, iy;
    token_cell(loc, token, b, ix, iy);
    const unsigned pos = atomicAdd(&Acur[b * HW_ + iy * W_ + ix], 1u);
    toks[pos] = (unsigned)token;
}

// Pass 4 (FUSED): gather 3 rows x 50 cols of per-cell means for a 64-channel
// group into LDS, then emit the final center-row values (mean if nonempty,
// gaussian-gated neighbor blend if empty) with a single coalesced NCHW write.
// OOB halo rows/cols are never gathered -> cflag==0 -> gate weight 0.
__global__ __launch_bounds__(256) void fused_k(const float* __restrict__ xf,
        const unsigned* __restrict__ Astart, const unsigned* __restrict__ toks,
        float* __restrict__ out) {
    const int blk = blockIdx.x;          // ((b*128 + y)*4 + cg)*2 + xh
    const int xh = blk & 1;
    const int cg = (blk >> 1) & 3;
    const int y  = (blk >> 3) & 127;
    const int b  = blk >> 10;
    const int xs = xh * XH_;
    const int lane = threadIdx.x & 63;
    const int wv = threadIdx.x >> 6;

    __shared__ float means[3][XS_][CP_];
    __shared__ unsigned cflag[3][XS_];

    // zero-init LDS
    {
        float* p = &means[0][0][0];
        for (int i = threadIdx.x; i < 3 * XS_ * CP_; i += 256) p[i] = 0.0f;
        unsigned* q = &cflag[0][0];
        for (int i = threadIdx.x; i < 3 * XS_; i += 256) q[i] = 0u;
    }
    __syncthreads();

    // gather: 150 cell-slots striped across the 4 waves; lane = channel
    for (int ci = wv; ci < 3 * XS_; ci += 4) {
        const int r  = ci / XS_;
        const int xi = ci - r * XS_;
        const int yg = y - 1 + r;
        const int xg = xs - 1 + xi;
        if ((unsigned)yg >= (unsigned)H_ || (unsigned)xg >= (unsigned)W_) continue;
        const int cell = b * HW_ + yg * W_ + xg;
        const unsigned p0 = Astart[cell], p1 = Astart[cell + 1];
        if (p0 == p1) continue;          // empty: LDS stays {0, cflag=0}
        float acc = 0.0f;
        for (unsigned p = p0; p < p1; ++p) {
            const unsigned tok = toks[p];
            acc += xf[(size_t)tok * C_ + cg * CG_ + lane];   // 256B coalesced
        }
        const float rcp = 1.0f / ((float)(p1 - p0) + EPSF);
        means[r][xi][lane] = acc * rcp;
        if (lane == 0) cflag[r][xi] = p1 - p0;
    }
    __syncthreads();

    // fill + write: 48 x * 64 ch = 3072 elems, 12 per thread, x-fastest
    #pragma unroll
    for (int i = 0; i < 12; ++i) {
        const int flat = i * 256 + threadIdx.x;
        const int c  = flat / XH_;       // 0..63
        const int xl = flat - c * XH_;   // 0..47
        const int xi = xl + 1;           // LDS column of the center cell
        float v;
        if (cflag[1][xi] != 0u) {
            v = means[1][xi][c];         // nonempty: normalized mean
        } else {
            const float w00 = cflag[0][xi - 1] ? KW2 : 0.0f;
            const float w01 = cflag[0][xi]     ? KW1 : 0.0f;
            const float w02 = cflag[0][xi + 1] ? KW2 : 0.0f;
            const float w10 = cflag[1][xi - 1] ? KW1 : 0.0f;
            const float w12 = cflag[1][xi + 1] ? KW1 : 0.0f;
            const float w20 = cflag[2][xi - 1] ? KW2 : 0.0f;
            const float w21 = cflag[2][xi]     ? KW1 : 0.0f;
            const float w22 = cflag[2][xi + 1] ? KW2 : 0.0f;
            const float ms = ((w00 + w02) + (w20 + w22)) + ((w01 + w21) + (w10 + w12));
            float fs = w00 * means[0][xi - 1][c];
            fs += w01 * means[0][xi][c];
            fs += w02 * means[0][xi + 1][c];
            fs += w10 * means[1][xi - 1][c];
            fs += w12 * means[1][xi + 1][c];
            fs += w20 * means[2][xi - 1][c];
            fs += w21 * means[2][xi][c];
            fs += w22 * means[2][xi + 1][c];
            v = fs * (1.0f / (ms + EPSF));   // ms==0 -> fs==0 -> 0
        }
        out[((size_t)(b * C_ + cg * CG_ + c)) * HW_ + y * W_ + xs + xl] = v;
    }
}

extern "C" void kernel_launch(void* const* d_in, const int* in_sizes, int n_in,
                              void* d_out, int out_size, void* d_ws, size_t ws_size,
                              hipStream_t stream) {
    const float* x   = (const float*)d_in[0];   // (B, N, C) f32
    const float* loc = (const float*)d_in[1];   // (B, N, 2) f32
    float* out = (float*)d_out;                 // (B, C, H, W) f32

    unsigned* W32 = (unsigned*)d_ws;
    unsigned* Astart = W32 + OFF_ASTART;
    unsigned* Acur   = W32 + OFF_ACUR;
    unsigned* Bsum   = W32 + OFF_BSUM;
    unsigned* Boff   = W32 + OFF_BOFF;
    unsigned* toks   = W32 + OFF_TOKS;

    hipMemsetAsync(Acur, 0, (size_t)NC_ * sizeof(unsigned), stream);

    count_k  <<<NT_ / 256, 256, 0, stream>>>(loc, Acur);
    scanA    <<<NC_ / 256, 256, 0, stream>>>(Acur, Bsum);
    scanB    <<<1, 512, 0, stream>>>(Bsum, Boff);
    scanC    <<<NC_ / 256, 256, 0, stream>>>(Boff, Astart, Acur);
    fill_bins<<<NT_ / 256, 256, 0, stream>>>(loc, Acur, toks);

    fused_k<<<B_ * H_ * 4 * 2, 256, 0, stream>>>(x, Astart, toks, out);
}

// Round 9
// 111.372 us; speedup vs baseline: 1.6704x; 1.6704x over previous
//
#include <hip/hip_runtime.h>

// Problem constants (fixed by setup_inputs in the reference)
#define B_  8
#define N_  3072
#define C_  256
#define H_  128
#define W_  96
#define HW_ (H_ * W_)
#define NC_ (B_ * HW_)          // 98304 cells (~78% EMPTY: 0.25 tokens/cell)
#define NT_ (B_ * N_)           // 24576 tokens
#define EPSF 1e-6f

// Gaussian 3x3, sigma=2 (normalized): center, edge, corner
#define KW0 0.13080118f
#define KW1 0.11543166f
#define KW2 0.10186807f

// fused-kernel tiling
#define CG_ 64                  // channels per block
#define XH_ 48                  // x half-width per block
#define XS_ 50                  // staged columns (48 + 2 halo)
#define CP_ 65                  // channel pad (bank-conflict-free)

// ws layout (u32 units) — identical to the round-4-proven 900,104 B layout.
#define OFF_ASTART 0
#define OFF_ACUR   (NC_ + 1)
#define OFF_BSUM   (2 * NC_ + 1)
#define OFF_BOFF   (2 * NC_ + 1 + 384)
#define OFF_TOKS   (2 * NC_ + 1 + 768)
// total = 2*NC_+1+768+NT_ = 221953 u32 = 887,812 B

__device__ __forceinline__ void token_cell(const float* __restrict__ loc, int token,
                                           int& b, int& ix, int& iy) {
    b = token / N_;
    const float lx = fminf(fmaxf(loc[2 * token + 0], -1.0f), 1.0f);
    const float ly = fminf(fmaxf(loc[2 * token + 1], -1.0f), 1.0f);
    const float px = 0.5f * (lx + 1.0f) * (float)W_ - 0.5f;
    const float py = 0.5f * (ly + 1.0f) * (float)H_ - 0.5f;
    ix = (int)rintf(px); ix = min(max(ix, 0), W_ - 1);   // rintf = round-half-even = jnp.round
    iy = (int)rintf(py); iy = min(max(iy, 0), H_ - 1);
}

// Pass 1: histogram tokens into cells
__global__ void count_k(const float* __restrict__ loc, unsigned* __restrict__ cnts) {
    const int token = blockIdx.x * 256 + threadIdx.x;   // NT_ threads
    int b, ix, iy;
    token_cell(loc, token, b, ix, iy);
    atomicAdd(&cnts[b * HW_ + iy * W_ + ix], 1u);
}

// Pass 2a: per-block (256-cell) sums
__global__ void scanA(const unsigned* __restrict__ cnts, unsigned* __restrict__ Bsum) {
    const int i = blockIdx.x * 256 + threadIdx.x;
    int c = (int)cnts[i];
    #pragma unroll
    for (int off = 32; off > 0; off >>= 1) c += __shfl_down(c, off, 64);
    __shared__ int s[4];
    if ((threadIdx.x & 63) == 0) s[threadIdx.x >> 6] = c;
    __syncthreads();
    if (threadIdx.x == 0) Bsum[blockIdx.x] = (unsigned)(s[0] + s[1] + s[2] + s[3]);
}

// Pass 2b: exclusive scan of the 384 block sums (single block)
__global__ void scanB(const unsigned* __restrict__ Bsum, unsigned* __restrict__ Boff) {
    __shared__ unsigned s[512];
    const int t = threadIdx.x;
    const unsigned v = (t < 384) ? Bsum[t] : 0u;
    s[t] = v;
    __syncthreads();
    #pragma unroll
    for (int off = 1; off < 512; off <<= 1) {
        const unsigned a = (t >= off) ? s[t - off] : 0u;
        __syncthreads();
        s[t] += a;
        __syncthreads();
    }
    if (t < 384) Boff[t] = s[t] - v;   // exclusive
}

// Pass 2c: per-block exclusive scan + block offset -> Astart (and cursor copy)
__global__ void scanC(const unsigned* __restrict__ Boff,
                      unsigned* __restrict__ Astart, unsigned* __restrict__ Acur) {
    __shared__ unsigned s[256];
    const int t = threadIdx.x;
    const int i = blockIdx.x * 256 + t;
    const unsigned v = Acur[i];        // counts currently live in Acur
    s[t] = v;
    __syncthreads();
    #pragma unroll
    for (int off = 1; off < 256; off <<= 1) {
        const unsigned a = (t >= off) ? s[t - off] : 0u;
        __syncthreads();
        s[t] += a;
        __syncthreads();
    }
    const unsigned excl = s[t] - v + Boff[blockIdx.x];
    Astart[i] = excl;
    Acur[i]   = excl;                  // cursor starts at bin start
    if (i == 0) Astart[NC_] = NT_;     // total
}

// Pass 3: scatter token ids (packed with x) into bins
__global__ void fill_bins(const float* __restrict__ loc,
                          unsigned* __restrict__ Acur, unsigned* __restrict__ toks) {
    const int token = blockIdx.x * 256 + threadIdx.x;
    int b, ix, iy;
    token_cell(loc, token, b, ix, iy);
    const unsigned pos = atomicAdd(&Acur[b * HW_ + iy * W_ + ix], 1u);
    toks[pos] = ((unsigned)ix << 20) | (unsigned)token;
}

// Pass 4 (FUSED): per block = (b, y, 64-ch group, x-half). Waves 0-2 each walk
// ONE row's contiguous CSR token range with batch-4 loads (toks broadcast,
// xf 256B-coalesced), flushing per-cell means into LDS on x-change. Then the
// block emits final center-row values (mean if nonempty, gaussian-gated blend
// if empty) with a single coalesced NCHW write. OOB halo -> cflag=0 -> w=0.
__global__ __launch_bounds__(256) void fused_k(const float* __restrict__ xf,
        const unsigned* __restrict__ Astart, const unsigned* __restrict__ toks,
        float* __restrict__ out) {
    const int blk = blockIdx.x;          // ((b*128 + y)*4 + cg)*2 + xh
    const int xh = blk & 1;
    const int cg = (blk >> 1) & 3;
    const int y  = (blk >> 3) & 127;
    const int b  = blk >> 10;
    const int xs = xh * XH_;
    const int lane = threadIdx.x & 63;
    const int wv = threadIdx.x >> 6;

    __shared__ float means[3][XS_][CP_];
    __shared__ unsigned cflag[3][XS_];

    // zero-init means (cflag fully overwritten below)
    {
        float* p = &means[0][0][0];
        for (int i = threadIdx.x; i < 3 * XS_ * CP_; i += 256) p[i] = 0.0f;
    }
    // stage cflag: 150 threads, one cell each (parallel coalesced Astart reads)
    if (threadIdx.x < 3 * XS_) {
        const int r  = threadIdx.x / XS_;
        const int xi = threadIdx.x - r * XS_;
        const int yg = y - 1 + r;
        const int xg = xs - 1 + xi;
        unsigned cf = 0u;
        if ((unsigned)yg < (unsigned)H_ && (unsigned)xg < (unsigned)W_) {
            const int cell = b * HW_ + yg * W_ + xg;
            cf = Astart[cell + 1] - Astart[cell];
        }
        cflag[r][xi] = cf;
    }
    __syncthreads();

    // gather: wave r in {0,1,2} walks row y-1+r's token range; lane = channel
    if (wv < 3) {
        const int yg = y - 1 + wv;
        if ((unsigned)yg < (unsigned)H_) {
            const int xg0 = (xs - 1 > 0) ? xs - 1 : 0;
            const int xg1 = (xs + XH_ < W_) ? xs + XH_ : W_ - 1;
            const int cell0 = b * HW_ + yg * W_ + xg0;
            const unsigned p0 = Astart[cell0];
            const unsigned p1 = Astart[cell0 + (xg1 - xg0) + 1];
            int cur_xi = -1;
            float acc = 0.0f;
            unsigned cnt = 0u;
            for (unsigned p = p0; p < p1; p += 4) {
                unsigned vv[4]; float ff[4];
                #pragma unroll
                for (int j = 0; j < 4; ++j)
                    if (p + j < p1) vv[j] = toks[p + j];
                #pragma unroll
                for (int j = 0; j < 4; ++j)
                    if (p + j < p1)
                        ff[j] = xf[(size_t)(vv[j] & 0xFFFFFu) * C_ + cg * CG_ + lane];
                #pragma unroll
                for (int j = 0; j < 4; ++j) {
                    if (p + j >= p1) break;
                    const int xi = (int)(vv[j] >> 20) - xs + 1;   // in [0, 50)
                    if (xi != cur_xi) {
                        if (cur_xi >= 0)
                            means[wv][cur_xi][lane] = acc / ((float)cnt + EPSF);
                        acc = 0.0f; cnt = 0u; cur_xi = xi;
                    }
                    acc += ff[j]; ++cnt;
                }
            }
            if (cur_xi >= 0)
                means[wv][cur_xi][lane] = acc / ((float)cnt + EPSF);
        }
    }
    __syncthreads();

    // fill + write: 48 x * 64 ch = 3072 elems, 12 per thread, x-fastest
    #pragma unroll
    for (int i = 0; i < 12; ++i) {
        const int flat = i * 256 + threadIdx.x;
        const int c  = flat / XH_;       // 0..63
        const int xl = flat - c * XH_;   // 0..47
        const int xi = xl + 1;           // LDS column of the center cell
        float v;
        if (cflag[1][xi] != 0u) {
            v = means[1][xi][c];         // nonempty: normalized mean
        } else {
            const float w00 = cflag[0][xi - 1] ? KW2 : 0.0f;
            const float w01 = cflag[0][xi]     ? KW1 : 0.0f;
            const float w02 = cflag[0][xi + 1] ? KW2 : 0.0f;
            const float w10 = cflag[1][xi - 1] ? KW1 : 0.0f;
            const float w12 = cflag[1][xi + 1] ? KW1 : 0.0f;
            const float w20 = cflag[2][xi - 1] ? KW2 : 0.0f;
            const float w21 = cflag[2][xi]     ? KW1 : 0.0f;
            const float w22 = cflag[2][xi + 1] ? KW2 : 0.0f;
            const float ms = ((w00 + w02) + (w20 + w22)) + ((w01 + w21) + (w10 + w12));
            float fs = w00 * means[0][xi - 1][c];
            fs += w01 * means[0][xi][c];
            fs += w02 * means[0][xi + 1][c];
            fs += w10 * means[1][xi - 1][c];
            fs += w12 * means[1][xi + 1][c];
            fs += w20 * means[2][xi - 1][c];
            fs += w21 * means[2][xi][c];
            fs += w22 * means[2][xi + 1][c];
            v = fs * (1.0f / (ms + EPSF));   // ms==0 -> fs==0 -> 0
        }
        out[((size_t)(b * C_ + cg * CG_ + c)) * HW_ + y * W_ + xs + xl] = v;
    }
}

extern "C" void kernel_launch(void* const* d_in, const int* in_sizes, int n_in,
                              void* d_out, int out_size, void* d_ws, size_t ws_size,
                              hipStream_t stream) {
    const float* x   = (const float*)d_in[0];   // (B, N, C) f32
    const float* loc = (const float*)d_in[1];   // (B, N, 2) f32
    float* out = (float*)d_out;                 // (B, C, H, W) f32

    unsigned* W32 = (unsigned*)d_ws;
    unsigned* Astart = W32 + OFF_ASTART;
    unsigned* Acur   = W32 + OFF_ACUR;
    unsigned* Bsum   = W32 + OFF_BSUM;
    unsigned* Boff   = W32 + OFF_BOFF;
    unsigned* toks   = W32 + OFF_TOKS;

    hipMemsetAsync(Acur, 0, (size_t)NC_ * sizeof(unsigned), stream);

    count_k  <<<NT_ / 256, 256, 0, stream>>>(loc, Acur);
    scanA    <<<NC_ / 256, 256, 0, stream>>>(Acur, Bsum);
    scanB    <<<1, 512, 0, stream>>>(Bsum, Boff);
    scanC    <<<NC_ / 256, 256, 0, stream>>>(Boff, Astart, Acur);
    fill_bins<<<NT_ / 256, 256, 0, stream>>>(loc, Acur, toks);

    fused_k<<<B_ * H_ * 4 * 2, 256, 0, stream>>>(x, Astart, toks, out);
}

// Round 10
// 80.321 us; speedup vs baseline: 2.3161x; 1.3866x over previous
//
#include <hip/hip_runtime.h>

// Problem constants (fixed by setup_inputs in the reference)
#define B_  8
#define N_  3072
#define C_  256
#define H_  128
#define W_  96
#define HW_ (H_ * W_)
#define NC_ (B_ * HW_)          // 98304 cells (~78% EMPTY: 0.25 tokens/cell)
#define NT_ (B_ * N_)           // 24576 tokens
#define EPSF 1e-6f

// Gaussian 3x3, sigma=2 (normalized): center, edge, corner
#define KW0 0.13080118f
#define KW1 0.11543166f
#define KW2 0.10186807f

// fused-kernel tiling: block = (b, y, x-tile of 32, 64-ch group)
#define CG_ 64                  // channels per block
#define XT_ 32                  // x columns written per block
#define XS_ 34                  // staged columns (32 + 2 halo)
#define CP_ 68                  // channel pad (multiple of 4 -> 16B-aligned rows)

// ws layout (u32 units) — identical to the round-4-proven 900,104 B layout.
#define OFF_ASTART 0
#define OFF_ACUR   (NC_ + 1)
#define OFF_BSUM   (2 * NC_ + 1)
#define OFF_BOFF   (2 * NC_ + 1 + 384)
#define OFF_TOKS   (2 * NC_ + 1 + 768)
// total = 2*NC_+1+768+NT_ = 221953 u32 = 887,812 B

__device__ __forceinline__ void token_cell(const float* __restrict__ loc, int token,
                                           int& b, int& ix, int& iy) {
    b = token / N_;
    const float lx = fminf(fmaxf(loc[2 * token + 0], -1.0f), 1.0f);
    const float ly = fminf(fmaxf(loc[2 * token + 1], -1.0f), 1.0f);
    const float px = 0.5f * (lx + 1.0f) * (float)W_ - 0.5f;
    const float py = 0.5f * (ly + 1.0f) * (float)H_ - 0.5f;
    ix = (int)rintf(px); ix = min(max(ix, 0), W_ - 1);   // rintf = round-half-even = jnp.round
    iy = (int)rintf(py); iy = min(max(iy, 0), H_ - 1);
}

// Pass 1: histogram tokens into cells
__global__ void count_k(const float* __restrict__ loc, unsigned* __restrict__ cnts) {
    const int token = blockIdx.x * 256 + threadIdx.x;   // NT_ threads
    int b, ix, iy;
    token_cell(loc, token, b, ix, iy);
    atomicAdd(&cnts[b * HW_ + iy * W_ + ix], 1u);
}

// Pass 2a: per-block (256-cell) sums
__global__ void scanA(const unsigned* __restrict__ cnts, unsigned* __restrict__ Bsum) {
    const int i = blockIdx.x * 256 + threadIdx.x;
    int c = (int)cnts[i];
    #pragma unroll
    for (int off = 32; off > 0; off >>= 1) c += __shfl_down(c, off, 64);
    __shared__ int s[4];
    if ((threadIdx.x & 63) == 0) s[threadIdx.x >> 6] = c;
    __syncthreads();
    if (threadIdx.x == 0) Bsum[blockIdx.x] = (unsigned)(s[0] + s[1] + s[2] + s[3]);
}

// Pass 2b: exclusive scan of the 384 block sums (single block)
__global__ void scanB(const unsigned* __restrict__ Bsum, unsigned* __restrict__ Boff) {
    __shared__ unsigned s[512];
    const int t = threadIdx.x;
    const unsigned v = (t < 384) ? Bsum[t] : 0u;
    s[t] = v;
    __syncthreads();
    #pragma unroll
    for (int off = 1; off < 512; off <<= 1) {
        const unsigned a = (t >= off) ? s[t - off] : 0u;
        __syncthreads();
        s[t] += a;
        __syncthreads();
    }
    if (t < 384) Boff[t] = s[t] - v;   // exclusive
}

// Pass 2c: per-block exclusive scan + block offset -> Astart (and cursor copy)
__global__ void scanC(const unsigned* __restrict__ Boff,
                      unsigned* __restrict__ Astart, unsigned* __restrict__ Acur) {
    __shared__ unsigned s[256];
    const int t = threadIdx.x;
    const int i = blockIdx.x * 256 + t;
    const unsigned v = Acur[i];        // counts currently live in Acur
    s[t] = v;
    __syncthreads();
    #pragma unroll
    for (int off = 1; off < 256; off <<= 1) {
        const unsigned a = (t >= off) ? s[t - off] : 0u;
        __syncthreads();
        s[t] += a;
        __syncthreads();
    }
    const unsigned excl = s[t] - v + Boff[blockIdx.x];
    Astart[i] = excl;
    Acur[i]   = excl;                  // cursor starts at bin start
    if (i == 0) Astart[NC_] = NT_;     // total
}

// Pass 3: scatter token ids (packed with x) into bins
__global__ void fill_bins(const float* __restrict__ loc,
                          unsigned* __restrict__ Acur, unsigned* __restrict__ toks) {
    const int token = blockIdx.x * 256 + threadIdx.x;
    int b, ix, iy;
    token_cell(loc, token, b, ix, iy);
    const unsigned pos = atomicAdd(&Acur[b * HW_ + iy * W_ + ix], 1u);
    toks[pos] = ((unsigned)ix << 20) | (unsigned)token;
}

// Pass 4 (FUSED): per block = (b, y, 32-col x-tile, 64-ch group).
// Gather: waves 0-2 each walk one row's contiguous CSR token range (batch-4,
// toks broadcast, xf 256B-coalesced), flushing per-cell means into LDS.
// Fill: thread <-> FIXED x column (weights decoded once), 8 channels each,
// float4 LDS reads, coalesced 4B NCHW stores. Single write of the output.
__global__ __launch_bounds__(256) void fused_k(const float* __restrict__ xf,
        const unsigned* __restrict__ Astart, const unsigned* __restrict__ toks,
        float* __restrict__ out) {
    const int blk = blockIdx.x;          // ((b*128 + y)*3 + xt)*4 + cg
    const int cg = blk & 3;
    const int t2 = blk >> 2;
    const int xt = t2 % 3;
    const int t3 = t2 / 3;
    const int y  = t3 & 127;
    const int b  = t3 >> 7;
    const int xs = xt * XT_;
    const int lane = threadIdx.x & 63;
    const int wv = threadIdx.x >> 6;

    __shared__ __align__(16) float means[3][XS_][CP_];
    __shared__ unsigned cflag[3][XS_];

    // zero-init means (float4)
    {
        float4* p4 = (float4*)&means[0][0][0];
        #pragma unroll
        for (int i = threadIdx.x; i < 3 * XS_ * CP_ / 4; i += 256)
            p4[i] = make_float4(0.f, 0.f, 0.f, 0.f);
    }
    // stage cflag: 102 threads, one cell each (parallel coalesced Astart reads)
    if (threadIdx.x < 3 * XS_) {
        const int r  = threadIdx.x / XS_;
        const int xi = threadIdx.x - r * XS_;
        const int yg = y - 1 + r;
        const int xg = xs - 1 + xi;
        unsigned cf = 0u;
        if ((unsigned)yg < (unsigned)H_ && (unsigned)xg < (unsigned)W_) {
            const int cell = b * HW_ + yg * W_ + xg;
            cf = Astart[cell + 1] - Astart[cell];
        }
        cflag[r][xi] = cf;
    }
    __syncthreads();

    // gather: wave r in {0,1,2} walks row y-1+r's token range; lane = channel
    if (wv < 3) {
        const int yg = y - 1 + wv;
        if ((unsigned)yg < (unsigned)H_) {
            const int xg0 = (xs - 1 > 0) ? xs - 1 : 0;
            const int xg1 = (xs + XT_ < W_) ? xs + XT_ : W_ - 1;
            const int cell0 = b * HW_ + yg * W_ + xg0;
            const unsigned p0 = Astart[cell0];
            const unsigned p1 = Astart[cell0 + (xg1 - xg0) + 1];
            int cur_xi = -1;
            float acc = 0.0f;
            unsigned cnt = 0u;
            for (unsigned p = p0; p < p1; p += 4) {
                unsigned vv[4]; float ff[4];
                #pragma unroll
                for (int j = 0; j < 4; ++j)
                    if (p + j < p1) vv[j] = toks[p + j];
                #pragma unroll
                for (int j = 0; j < 4; ++j)
                    if (p + j < p1)
                        ff[j] = xf[(size_t)(vv[j] & 0xFFFFFu) * C_ + cg * CG_ + lane];
                #pragma unroll
                for (int j = 0; j < 4; ++j) {
                    if (p + j >= p1) break;
                    const int xi = (int)(vv[j] >> 20) - xs + 1;   // in [0, 34)
                    if (xi != cur_xi) {
                        if (cur_xi >= 0)
                            means[wv][cur_xi][lane] = acc / ((float)cnt + EPSF);
                        acc = 0.0f; cnt = 0u; cur_xi = xi;
                    }
                    acc += ff[j]; ++cnt;
                }
            }
            if (cur_xi >= 0)
                means[wv][cur_xi][lane] = acc / ((float)cnt + EPSF);
        }
    }
    __syncthreads();

    // fill + write: thread = fixed x column (xl), 8 channels (sub*8..sub*8+7)
    const int xl  = threadIdx.x & 31;
    const int sub = threadIdx.x >> 5;
    const int xi  = xl + 1;              // LDS column of the center cell
    const int c0  = sub * 8;
    float* op = out + ((size_t)(b * C_ + cg * CG_ + c0)) * HW_ + y * W_ + xs + xl;

    if (cflag[1][xi] != 0u) {            // nonempty: copy normalized mean
        #pragma unroll
        for (int q = 0; q < 2; ++q) {
            const float4 m = *(const float4*)&means[1][xi][c0 + q * 4];
            op[(size_t)(q * 4 + 0) * HW_] = m.x;
            op[(size_t)(q * 4 + 1) * HW_] = m.y;
            op[(size_t)(q * 4 + 2) * HW_] = m.z;
            op[(size_t)(q * 4 + 3) * HW_] = m.w;
        }
    } else {                             // empty: gaussian-gated neighbor blend
        const float w00 = cflag[0][xi - 1] ? KW2 : 0.0f;
        const float w01 = cflag[0][xi]     ? KW1 : 0.0f;
        const float w02 = cflag[0][xi + 1] ? KW2 : 0.0f;
        const float w10 = cflag[1][xi - 1] ? KW1 : 0.0f;
        const float w12 = cflag[1][xi + 1] ? KW1 : 0.0f;
        const float w20 = cflag[2][xi - 1] ? KW2 : 0.0f;
        const float w21 = cflag[2][xi]     ? KW1 : 0.0f;
        const float w22 = cflag[2][xi + 1] ? KW2 : 0.0f;
        const float ms = ((w00 + w02) + (w20 + w22)) + ((w01 + w21) + (w10 + w12));
        const float inv = 1.0f / (ms + EPSF);   // ms==0 -> fs==0 -> 0
        #pragma unroll
        for (int q = 0; q < 2; ++q) {
            const int cq = c0 + q * 4;
            const float4 a0 = *(const float4*)&means[0][xi - 1][cq];
            const float4 a1 = *(const float4*)&means[0][xi    ][cq];
            const float4 a2 = *(const float4*)&means[0][xi + 1][cq];
            const float4 b0 = *(const float4*)&means[1][xi - 1][cq];
            const float4 b2 = *(const float4*)&means[1][xi + 1][cq];
            const float4 d0 = *(const float4*)&means[2][xi - 1][cq];
            const float4 d1 = *(const float4*)&means[2][xi    ][cq];
            const float4 d2 = *(const float4*)&means[2][xi + 1][cq];
            float4 fs;
            fs.x = w00*a0.x + w01*a1.x + w02*a2.x + w10*b0.x + w12*b2.x + w20*d0.x + w21*d1.x + w22*d2.x;
            fs.y = w00*a0.y + w01*a1.y + w02*a2.y + w10*b0.y + w12*b2.y + w20*d0.y + w21*d1.y + w22*d2.y;
            fs.z = w00*a0.z + w01*a1.z + w02*a2.z + w10*b0.z + w12*b2.z + w20*d0.z + w21*d1.z + w22*d2.z;
            fs.w = w00*a0.w + w01*a1.w + w02*a2.w + w10*b0.w + w12*b2.w + w20*d0.w + w21*d1.w + w22*d2.w;
            op[(size_t)(q * 4 + 0) * HW_] = fs.x * inv;
            op[(size_t)(q * 4 + 1) * HW_] = fs.y * inv;
            op[(size_t)(q * 4 + 2) * HW_] = fs.z * inv;
            op[(size_t)(q * 4 + 3) * HW_] = fs.w * inv;
        }
    }
}

extern "C" void kernel_launch(void* const* d_in, const int* in_sizes, int n_in,
                              void* d_out, int out_size, void* d_ws, size_t ws_size,
                              hipStream_t stream) {
    const float* x   = (const float*)d_in[0];   // (B, N, C) f32
    const float* loc = (const float*)d_in[1];   // (B, N, 2) f32
    float* out = (float*)d_out;                 // (B, C, H, W) f32

    unsigned* W32 = (unsigned*)d_ws;
    unsigned* Astart = W32 + OFF_ASTART;
    unsigned* Acur   = W32 + OFF_ACUR;
    unsigned* Bsum   = W32 + OFF_BSUM;
    unsigned* Boff   = W32 + OFF_BOFF;
    unsigned* toks   = W32 + OFF_TOKS;

    hipMemsetAsync(Acur, 0, (size_t)NC_ * sizeof(unsigned), stream);

    count_k  <<<NT_ / 256, 256, 0, stream>>>(loc, Acur);
    scanA    <<<NC_ / 256, 256, 0, stream>>>(Acur, Bsum);
    scanB    <<<1, 512, 0, stream>>>(Bsum, Boff);
    scanC    <<<NC_ / 256, 256, 0, stream>>>(Boff, Astart, Acur);
    fill_bins<<<NT_ / 256, 256, 0, stream>>>(loc, Acur, toks);

    fused_k<<<B_ * H_ * 3 * 4, 256, 0, stream>>>(x, Astart, toks, out);
}